// Round 5
// baseline (135.150 us; speedup 1.0000x reference)
//
#include <hip/hip_runtime.h>

#define CAS(a, b) { float _t = fminf(a, b); (b) = fmaxf(a, b); (a) = _t; }
#define MED3(a,b,c) __builtin_amdgcn_fmed3f((a),(b),(c))

#define IMG    1024
#define TW     128           // output tile width (4 px per thread * 32 threads)
#define TH     8             // output tile height
#define RAW_W  136           // raw tile cols: gx in [x0-4, x0+132)
#define RAW_H  12            // rows: gy in [y0-2, y0+10)

__device__ __forceinline__ void sort5(float& a0, float& a1, float& a2, float& a3, float& a4) {
    // optimal 9-comparator 5-sort
    CAS(a0, a1); CAS(a3, a4); CAS(a2, a4); CAS(a2, a3);
    CAS(a0, a3); CAS(a0, a2); CAS(a1, a4); CAS(a1, a3); CAS(a1, a2);
}

// Median of 25 from the 13 candidates of a doubly-sorted 5x5.
// cd = [a03,a04, a12,a13,a14, a21,a22,a23, a30,a31,a32, a40,a41]
// Uses column relations a03<=a13, a04<=a14, a30<=a40, a31<=a41 and the
// two-sorted-list rank identity rank_k = max_{i+j=k} min(A_i, C_j)
// (out-of-range indices -> the other list's element).
__device__ __forceinline__ float tail13v(const float* cd) {
    float e0 = cd[0],  e1 = cd[1];                    // row0 top-2 (sorted)
    float f0 = cd[2],  f1 = cd[3],  f2 = cd[4];       // row1 top-3 (sorted)
    float h0 = cd[5],  h1 = cd[6],  h2 = cd[7];       // row2 mid-3 (sorted)
    float g0 = cd[8],  g1 = cd[9],  g2 = cd[10];      // row3 bot-3 (sorted)
    float k0 = cd[11], k1 = cd[12];                   // row4 bot-2 (sorted)

    // A = sorted merge of {e0,e1} and {f0,f1,f2}  (e0<=f1, e1<=f2)
    float A0 = fminf(e0, f0), M = fmaxf(e0, f0);
    float A4 = f2;
    float A3 = fmaxf(e1, f1);
    float A1 = fminf(fminf(M, e1), f1);
    float A2 = MED3(e1, f1, M);
    // C = sorted merge of {g0,g1,g2} and {k0,k1}  (g0<=k0, g1<=k1)
    float C0 = g0;
    float C4 = fmaxf(g2, k1);
    float C1 = fminf(g1, k0);
    float mgk = fminf(g2, k1);
    float C3 = fmaxf(fmaxf(mgk, g1), k0);
    float C2 = MED3(g1, k0, mgk);
    // ranks 3..6 of the 10 = A ∪ C
    float r3 = fmaxf(fmaxf(fmaxf(fminf(A0, C3), fminf(A1, C2)), fminf(A2, C1)), fminf(A3, C0));
    float r4 = fmaxf(fmaxf(fmaxf(fminf(A0, C4), fminf(A1, C3)), fminf(A2, C2)),
                     fmaxf(fminf(A3, C1), fminf(A4, C0)));
    float r5 = fmaxf(fmaxf(fmaxf(fminf(A1, C4), fminf(A2, C3)), fminf(A3, C2)),
                     fmaxf(fmaxf(fminf(A4, C1), A0), C0));
    float r6 = fmaxf(fmaxf(fmaxf(fminf(A2, C4), fminf(A3, C3)), fminf(A4, C2)),
                     fmaxf(A1, C1));
    // rank 6 (0-indexed) of the 13 = median of 25
    return fmaxf(fmaxf(fmaxf(fminf(r4, h2), fminf(r5, h1)), fminf(r6, h0)), r3);
}

__global__ __launch_bounds__(256, 4)
void median5x5_kernel(const float* __restrict__ in, float* __restrict__ out) {
    __shared__ float tile[RAW_H][RAW_W];         // 6528 B
    __shared__ float scol[5][TH][RAW_W];         // 21760 B

    const int tx  = threadIdx.x;                 // 0..31
    const int ty  = threadIdx.y;                 // 0..7
    const int tid = ty * 32 + tx;
    const int x0  = blockIdx.x * TW;
    const int y0  = blockIdx.y * TH;
    const float* plane = in + (size_t)blockIdx.z * (IMG * IMG);

    // ---- phase A: vectorized halo load (float4 chunks are all-in or all-out) ----
    #pragma unroll
    for (int t = tid; t < RAW_H * (RAW_W / 4); t += 256) {   // 12*34 = 408 tasks
        int r   = t / 34;
        int k   = t - r * 34;
        int gy  = y0 - 2 + r;
        int gx0 = x0 - 4 + 4 * k;
        float4 v = make_float4(0.f, 0.f, 0.f, 0.f);
        if ((unsigned)gy < IMG && (unsigned)gx0 < IMG)
            v = *(const float4*)(plane + (size_t)gy * IMG + gx0);
        *(float4*)&tile[r][4 * k] = v;
    }
    __syncthreads();

    // ---- phase B: dual-column sorts (cols 2..133 as 66 pairs, b64 in/out) ----
    for (int p = tx; p < 66; p += 32) {
        int c = 2 * p + 2;
        float2 r0 = *(const float2*)&tile[ty + 0][c];
        float2 r1 = *(const float2*)&tile[ty + 1][c];
        float2 r2 = *(const float2*)&tile[ty + 2][c];
        float2 r3 = *(const float2*)&tile[ty + 3][c];
        float2 r4 = *(const float2*)&tile[ty + 4][c];
        sort5(r0.x, r1.x, r2.x, r3.x, r4.x);
        sort5(r0.y, r1.y, r2.y, r3.y, r4.y);
        *(float2*)&scol[0][ty][c] = r0;
        *(float2*)&scol[1][ty][c] = r1;
        *(float2*)&scol[2][ty][c] = r2;
        *(float2*)&scol[3][ty][c] = r3;
        *(float2*)&scol[4][ty][c] = r4;
    }
    __syncthreads();

    // ---- phase C/D: per rank-row read 8 cols; shared sort4s + med3 insertion
    //      extract candidates for 4 pixels (outputs x0+4tx .. x0+4tx+3) ----
    const int cb = 4 * tx + 2;
    float cd[4][13];

    #pragma unroll
    for (int i = 0; i < 5; ++i) {
        const float* rp = &scol[i][ty][cb];
        float2 u0 = *(const float2*)(rp);
        float2 u1 = *(const float2*)(rp + 2);
        float2 u2 = *(const float2*)(rp + 4);
        float2 u3 = *(const float2*)(rp + 6);
        float c0 = u0.x, c1 = u0.y, c2 = u1.x, c3 = u1.y;
        float c4 = u2.x, c5 = u2.y, c6 = u3.x, c7 = u3.y;

        // shared sort2 of (c3,c4)
        float m0 = c3, m1 = c4; CAS(m0, m1);
        // S = sorted4(c1..c4) = merge(sort2(c1,c2), (m0,m1))
        float a = c1, b = c2; CAS(a, b);
        float s0 = fminf(a, m0), t1 = fmaxf(a, m0);
        float t2 = fminf(b, m1), s3 = fmaxf(b, m1);
        float s1 = fminf(t1, t2), s2 = fmaxf(t1, t2);
        // T = sorted4(c3..c6) = merge((m0,m1), sort2(c5,c6))
        float d = c5, e = c6; CAS(d, e);
        float q0 = fminf(m0, d), w1 = fmaxf(m0, d);
        float w2 = fminf(m1, e), q3 = fmaxf(m1, e);
        float q1 = fminf(w1, w2), q2 = fmaxf(w1, w2);

        // insertion of x into sorted4 (s0..s3): rank_k -> min / med3 / max
#define EXT(px, S0, S1, S2, S3, X) { \
        if (i == 0)      { cd[px][0]  = MED3(S2, S3, X); cd[px][1]  = fmaxf(S3, X); } \
        else if (i == 1) { cd[px][2]  = MED3(S1, S2, X); cd[px][3]  = MED3(S2, S3, X); cd[px][4] = fmaxf(S3, X); } \
        else if (i == 2) { cd[px][5]  = MED3(S0, S1, X); cd[px][6]  = MED3(S1, S2, X); cd[px][7] = MED3(S2, S3, X); } \
        else if (i == 3) { cd[px][8]  = fminf(S0, X);    cd[px][9]  = MED3(S0, S1, X); cd[px][10] = MED3(S1, S2, X); } \
        else             { cd[px][11] = fminf(S0, X);    cd[px][12] = MED3(S0, S1, X); } }
        EXT(0, s0, s1, s2, s3, c0)    // window c0..c4
        EXT(1, s0, s1, s2, s3, c5)    // window c1..c5
        EXT(2, q0, q1, q2, q3, c2)    // window c2..c6
        EXT(3, q0, q1, q2, q3, c7)    // window c3..c7
#undef EXT
    }

    float4 o;
    o.x = tail13v(cd[0]);
    o.y = tail13v(cd[1]);
    o.z = tail13v(cd[2]);
    o.w = tail13v(cd[3]);
    *(float4*)(out + (size_t)blockIdx.z * (IMG * IMG) + (size_t)(y0 + ty) * IMG + x0 + 4 * tx) = o;
}

extern "C" void kernel_launch(void* const* d_in, const int* in_sizes, int n_in,
                              void* d_out, int out_size, void* d_ws, size_t ws_size,
                              hipStream_t stream) {
    const float* in  = (const float*)d_in[0];
    float*       out = (float*)d_out;
    dim3 block(32, TH, 1);                       // 256 threads
    dim3 grid(IMG / TW, IMG / TH, 12);           // 8 x 128 x (B*C)
    hipLaunchKernelGGL(median5x5_kernel, grid, block, 0, stream, in, out);
}